// Round 1
// baseline (259.656 us; speedup 1.0000x reference)
//
#include <hip/hip_runtime.h>
#include <math.h>

// DynamicHybridRouter: logits = x @ gate_w^T + gate_b; top-2 routing (or temp softmax
// if any expert immature). x:[16384,2048] f32, gate_w:[64,2048] f32, gate_b:[64] f32,
// expert_maturity:[64] i32. out:[16384,64] f32.
//
// Design: 512 blocks x 256 threads. Block = 32 rows x 64 experts, split-K over the
// 4 waves (each wave: K-slice of 512). Per-thread register tile 8 rows x 4 experts.
// w staged per-wave in LDS (XOR-swizzled float4 groups -> conflict-free compute reads);
// x streamed straight from global (16-way broadcast within wave, each byte read once).
// Epilogue: LDS cross-wave reduction + bias, then top-2/softmax routing in-block.

#define NROWS 16384
#define DIM   2048
#define NEXP  64
#define BM    32            // rows per block
#define KSLICE 512          // K depth per wave
#define BK    32            // K chunk staged per iteration
#define NCHUNK (KSLICE / BK) // 16

__global__ __launch_bounds__(256, 2)
void router_kernel(const float* __restrict__ x,
                   const float* __restrict__ gw,
                   const float* __restrict__ gb,
                   const int* __restrict__ mat,
                   float* __restrict__ out) {
  // Per-wave w slab: 64 experts x BK floats = 2048 floats (8KB); 4 waves = 32KB.
  // Reused after the K loop as 4 partial-logit slabs of 32x64 = 2048 floats each.
  __shared__ float slab[4 * NEXP * BK];
  __shared__ float p_a[BM], p_b[BM];
  __shared__ int   p_i[BM], p_j[BM];
  __shared__ int   s_flag;

  const int tid  = threadIdx.x;
  const int wave = tid >> 6;
  const int lane = tid & 63;
  const int te   = lane & 15;   // expert group: experts 4*te .. 4*te+3
  const int tr   = lane >> 4;   // row group: rows 8*tr .. 8*tr+7
  const int g    = te & 7;      // LDS swizzle group
  const int row0 = blockIdx.x * BM;
  const int kbase = wave * KSLICE;

  // maturity flag: any immature expert? (wave 0 only; consumed after barriers)
  if (wave == 0) {
    unsigned long long b = __ballot(mat[lane] == 0);
    if (lane == 0) s_flag = (b != 0ull) ? 1 : 0;
  }

  float acc[8][4];
#pragma unroll
  for (int i = 0; i < 8; ++i)
#pragma unroll
    for (int j = 0; j < 4; ++j) acc[i][j] = 0.0f;

  float* wslab = slab + wave * (NEXP * BK);

  for (int c = 0; c < NCHUNK; ++c) {
    const int koff = kbase + c * BK;
    __syncthreads();  // protect slab vs previous chunk's readers
    // stage w chunk: 64 experts x 32 floats, float4-coalesced global reads,
    // XOR-swizzled LDS layout (k4' = k4 ^ ((e/4)&7)) for conflict-free compute reads
#pragma unroll
    for (int it = 0; it < 8; ++it) {
      int f  = it * 64 + lane;  // float4 index 0..511
      int e  = f >> 3;
      int k4 = f & 7;
      float4 v = *(const float4*)(gw + (size_t)e * DIM + koff + 4 * k4);
      *(float4*)(wslab + e * BK + 4 * (k4 ^ ((e >> 2) & 7))) = v;
    }
    __syncthreads();
    // compute: per k4-step, 4 LDS b128 (w) + 8 global b128 (x, broadcast) + 128 FMA
#pragma unroll 4
    for (int k4 = 0; k4 < 8; ++k4) {
      float4 bw[4];
#pragma unroll
      for (int j = 0; j < 4; ++j)
        bw[j] = *(const float4*)(wslab + (4 * te + j) * BK + 4 * (k4 ^ g));
#pragma unroll
      for (int i = 0; i < 8; ++i) {
        const float4 bx = *(const float4*)(x + (size_t)(row0 + 8 * tr + i) * DIM + koff + 4 * k4);
#pragma unroll
        for (int j = 0; j < 4; ++j) {
          acc[i][j] = fmaf(bx.x, bw[j].x,
                      fmaf(bx.y, bw[j].y,
                      fmaf(bx.z, bw[j].z,
                      fmaf(bx.w, bw[j].w, acc[i][j]))));
        }
      }
    }
  }

  // write this wave's partial logits into its own slab (same region it was reading —
  // same-wave program order, no barrier needed before the write)
#pragma unroll
  for (int i = 0; i < 8; ++i) {
    float4 v = make_float4(acc[i][0], acc[i][1], acc[i][2], acc[i][3]);
    *(float4*)(wslab + (8 * tr + i) * NEXP + 4 * te) = v;
  }
  __syncthreads();

  // cross-wave reduction + bias into slab[0 .. 2047]
  for (int idx = tid; idx < BM * NEXP; idx += 256) {
    float v = slab[idx] + slab[2048 + idx] + slab[4096 + idx] + slab[6144 + idx]
            + gb[idx & (NEXP - 1)];
    slab[idx] = v;
  }
  __syncthreads();

  const int flag = s_flag;

  // per-row routing parameters (threads 0..31, one row each; rotated scan order
  // breaks the 32-way LDS bank conflict of a straight row scan)
  if (tid < BM) {
    const float* rowp = slab + tid * NEXP;
    if (flag == 0) {
      float m1 = -1e30f, m2 = -1e30f;
      int i1 = 0, i2 = 0;
      for (int ee = 0; ee < NEXP; ++ee) {
        int e = (ee + tid) & (NEXP - 1);
        float v = rowp[e];
        if (v > m1) { m2 = m1; i2 = i1; m1 = v; i1 = e; }
        else if (v > m2) { m2 = v; i2 = e; }
      }
      float t = expf(m2 - m1);          // softmax over the two raw top logits
      float pa = 1.0f / (1.0f + t);
      p_a[tid] = pa;
      p_b[tid] = t * pa;
      p_i[tid] = i1;
      p_j[tid] = i2;
    } else {
      float mx = -1e30f;
      for (int ee = 0; ee < NEXP; ++ee) {
        int e = (ee + tid) & (NEXP - 1);
        mx = fmaxf(mx, rowp[e]);
      }
      float s = 0.0f;
      for (int ee = 0; ee < NEXP; ++ee) {
        int e = (ee + tid) & (NEXP - 1);
        s += expf((rowp[e] - mx) * 0.5f);  // /TEMPERATURE=2.0
      }
      p_a[tid] = mx;
      p_b[tid] = 1.0f / s;
    }
  }
  __syncthreads();

  // coalesced float4 output writes of the 32x64 tile
  if (flag == 0) {
    for (int q = tid; q < BM * NEXP / 4; q += 256) {
      int r  = q >> 4;
      int e0 = (q & 15) * 4;
      int i1 = p_i[r], i2 = p_j[r];
      float a = p_a[r], b = p_b[r];
      float4 v;
      v.x = (e0 + 0 == i1) ? a : (e0 + 0 == i2) ? b : 0.0f;
      v.y = (e0 + 1 == i1) ? a : (e0 + 1 == i2) ? b : 0.0f;
      v.z = (e0 + 2 == i1) ? a : (e0 + 2 == i2) ? b : 0.0f;
      v.w = (e0 + 3 == i1) ? a : (e0 + 3 == i2) ? b : 0.0f;
      *(float4*)(out + (size_t)(row0 + r) * NEXP + e0) = v;
    }
  } else {
    for (int q = tid; q < BM * NEXP / 4; q += 256) {
      int r  = q >> 4;
      int e0 = (q & 15) * 4;
      float mx = p_a[r], inv = p_b[r];
      float4 lv = *(const float4*)(slab + r * NEXP + e0);
      float4 v;
      v.x = expf((lv.x - mx) * 0.5f) * inv;
      v.y = expf((lv.y - mx) * 0.5f) * inv;
      v.z = expf((lv.z - mx) * 0.5f) * inv;
      v.w = expf((lv.w - mx) * 0.5f) * inv;
      *(float4*)(out + (size_t)(row0 + r) * NEXP + e0) = v;
    }
  }
}

extern "C" void kernel_launch(void* const* d_in, const int* in_sizes, int n_in,
                              void* d_out, int out_size, void* d_ws, size_t ws_size,
                              hipStream_t stream) {
  const float* x  = (const float*)d_in[0];
  const float* gw = (const float*)d_in[1];
  const float* gb = (const float*)d_in[2];
  const int*   mt = (const int*)d_in[3];
  float* outp = (float*)d_out;
  (void)in_sizes; (void)n_in; (void)d_ws; (void)ws_size; (void)out_size;

  dim3 grid(NROWS / BM);   // 512 blocks
  dim3 block(256);
  router_kernel<<<grid, block, 0, stream>>>(x, gw, gb, mt, outp);
}